// Round 1
// baseline (100.157 us; speedup 1.0000x reference)
//
#include <hip/hip_runtime.h>
#include <math.h>

#define DIMC 768
#define BATCH 16
#define HWSZ 1024
#define WID 32
#define NT 32

// out layout: result [16*32*768] | p [16*32*768] | mask [16*32*1024]
#define OUT_P_OFF   393216
#define OUT_MASK_OFF 786432

// ---------------- K1: BN + depthwise 3x3 + hardswish ----------------
// one block per (b,c) plane of 32x32
__global__ __launch_bounds__(256) void k1_bn_dw_hsw(
    const float* __restrict__ x,
    const float* __restrict__ bnw, const float* __restrict__ bnb,
    const float* __restrict__ bnm, const float* __restrict__ bnv,
    const float* __restrict__ dww, const float* __restrict__ dwb,
    float* __restrict__ h)
{
    int bc = blockIdx.x;            // b*768 + c
    int c  = bc & (DIMC - 1);       // 768 = pow2? 768 is NOT pow2
    c = bc % DIMC;
    __shared__ float tile[32][33];

    float scale = bnw[c] * rsqrtf(bnv[c] + 1e-5f);
    float shift = bnb[c] - bnm[c] * scale;

    const float* xp = x + (size_t)bc * HWSZ;
    int tid = threadIdx.x;
    for (int i = tid; i < HWSZ; i += 256) {
        tile[i >> 5][i & 31] = xp[i] * scale + shift;
    }
    __syncthreads();

    float w[9];
#pragma unroll
    for (int k = 0; k < 9; ++k) w[k] = dww[c * 9 + k];
    float bias = dwb[c];

    float* hp = h + (size_t)bc * HWSZ;
    for (int i = tid; i < HWSZ; i += 256) {
        int r = i >> 5, col = i & 31;
        float acc = bias;
#pragma unroll
        for (int dr = -1; dr <= 1; ++dr) {
#pragma unroll
            for (int dc = -1; dc <= 1; ++dc) {
                int rr = r + dr, cc2 = col + dc;
                if (rr >= 0 && rr < 32 && cc2 >= 0 && cc2 < 32)
                    acc += tile[rr][cc2] * w[(dr + 1) * 3 + (dc + 1)];
            }
        }
        float t = fminf(fmaxf(acc + 3.0f, 0.0f), 6.0f);
        hp[i] = acc * t * (1.0f / 6.0f);
    }
}

// ---------------- K_init: s = pw_bias broadcast ----------------
__global__ __launch_bounds__(256) void k_init_s(
    const float* __restrict__ pwb, float* __restrict__ s)
{
    int i = blockIdx.x * 256 + threadIdx.x;   // < 16*32*1024
    int t = (i >> 10) & 31;
    s[i] = pwb[t];
}

// ---------------- K2: pointwise 768->32, channel-split, atomic accumulate ----
// grid (poschunk=8, cchunk=8, b=16), block 128 threads (one pos each)
__global__ __launch_bounds__(128) void k2_pointwise(
    const float* __restrict__ h, const float* __restrict__ pww,
    float* __restrict__ s)
{
    int b  = blockIdx.z;
    int cc = blockIdx.y;            // channel chunk: 96 channels
    int pos = blockIdx.x * 128 + threadIdx.x;

    const float* hp = h + ((size_t)b * DIMC + cc * 96) * HWSZ + pos;
    const float* wp = pww + cc * 96;        // pww[t*768 + c]

    float acc[NT];
#pragma unroll
    for (int t = 0; t < NT; ++t) acc[t] = 0.0f;

    for (int c = 0; c < 96; ++c) {
        float hv = hp[(size_t)c * HWSZ];
#pragma unroll
        for (int t = 0; t < NT; ++t)
            acc[t] += hv * wp[t * DIMC + c];   // block-uniform address -> s_load
    }

    float* sp = s + (size_t)b * NT * HWSZ + pos;
#pragma unroll
    for (int t = 0; t < NT; ++t)
        atomicAdd(sp + (size_t)t * HWSZ, acc[t]);
}

// ---------------- K3: argmax mask + gather-sum ----------------
// one block per (b,t) row of 1024 positions
__global__ __launch_bounds__(256) void k3_mask_gather(
    const float* __restrict__ s,
    const float* __restrict__ x, const float* __restrict__ posin,
    const float* __restrict__ bnw, const float* __restrict__ bnb,
    const float* __restrict__ bnm, const float* __restrict__ bnv,
    float* __restrict__ out)
{
    int bt = blockIdx.x;           // b*32 + t
    int b  = bt >> 5;
    int tid = threadIdx.x;

    const float* sp = s + (size_t)bt * HWSZ;
    float v[4];
    float m = -INFINITY;
#pragma unroll
    for (int i = 0; i < 4; ++i) {
        v[i] = sp[tid + 256 * i];
        m = fmaxf(m, v[i]);
    }
    // wave64 reduce
#pragma unroll
    for (int off = 32; off; off >>= 1)
        m = fmaxf(m, __shfl_xor(m, off));
    __shared__ float wm[4];
    if ((tid & 63) == 0) wm[tid >> 6] = m;
    __syncthreads();
    m = fmaxf(fmaxf(wm[0], wm[1]), fmaxf(wm[2], wm[3]));

    __shared__ int nmatch;
    __shared__ int matchpos[16];
    if (tid == 0) nmatch = 0;
    __syncthreads();

    float* maskp = out + OUT_MASK_OFF + (size_t)bt * HWSZ;
#pragma unroll
    for (int i = 0; i < 4; ++i) {
        int pos = tid + 256 * i;
        int hit = (v[i] == m);
        maskp[pos] = hit ? 1.0f : 0.0f;
        if (hit) {
            int k = atomicAdd(&nmatch, 1);
            if (k < 16) matchpos[k] = pos;
        }
    }
    __syncthreads();
    int nm = nmatch < 16 ? nmatch : 16;

    const float* xb = x + (size_t)b * DIMC * HWSZ;
    const float* pb = posin + (size_t)b * DIMC * HWSZ;
    for (int c = tid; c < DIMC; c += 256) {
        float scale = bnw[c] * rsqrtf(bnv[c] + 1e-5f);
        float shift = bnb[c] - bnm[c] * scale;
        float rf = 0.0f, rp = 0.0f;
        for (int k = 0; k < nm; ++k) {
            int pos = matchpos[k];
            rf += xb[(size_t)c * HWSZ + pos] * scale + shift;
            rp += pb[(size_t)c * HWSZ + pos];
        }
        out[(size_t)bt * DIMC + c] = rf;
        out[OUT_P_OFF + (size_t)bt * DIMC + c] = rp;
    }
}

extern "C" void kernel_launch(void* const* d_in, const int* in_sizes, int n_in,
                              void* d_out, int out_size, void* d_ws, size_t ws_size,
                              hipStream_t stream)
{
    const float* x    = (const float*)d_in[0];
    const float* pos  = (const float*)d_in[1];
    const float* bnw  = (const float*)d_in[2];
    const float* bnb  = (const float*)d_in[3];
    const float* bnm  = (const float*)d_in[4];
    const float* bnv  = (const float*)d_in[5];
    const float* dww  = (const float*)d_in[6];
    const float* dwb  = (const float*)d_in[7];
    const float* pww  = (const float*)d_in[8];
    const float* pwb  = (const float*)d_in[9];
    float* out = (float*)d_out;

    float* h = (float*)d_ws;                                   // 16*768*1024 f32 = 50.3 MB
    float* s = (float*)((char*)d_ws + (size_t)BATCH * DIMC * HWSZ * 4); // 16*32*1024 f32 = 2 MB

    k1_bn_dw_hsw<<<BATCH * DIMC, 256, 0, stream>>>(x, bnw, bnb, bnm, bnv, dww, dwb, h);
    k_init_s<<<(BATCH * NT * HWSZ) / 256, 256, 0, stream>>>(pwb, s);
    k2_pointwise<<<dim3(8, 8, BATCH), 128, 0, stream>>>(h, pww, s);
    k3_mask_gather<<<BATCH * NT, 256, 0, stream>>>(s, x, pos, bnw, bnb, bnm, bnv, out);
}